// Round 10
// baseline (78.465 us; speedup 1.0000x reference)
//
#include <hip/hip_runtime.h>

#define N 8192
#define DIM 64

typedef float f32x4 __attribute__((ext_vector_type(4)));
typedef short bf16x8 __attribute__((ext_vector_type(8)));

__device__ __forceinline__ unsigned short f32_to_bf16_rne(float f) {
  unsigned int u = __float_as_uint(f);
  unsigned int r = (u + 0x7FFFu + ((u >> 16) & 1u)) >> 16;
  return (unsigned short)r;
}

// Convert 8 consecutive f32 -> bf16x8 fragment (same RNE as prior rounds).
__device__ __forceinline__ bf16x8 cvt8(const float* __restrict__ p) {
  f32x4 lo = *reinterpret_cast<const f32x4*>(p);
  f32x4 hi = *reinterpret_cast<const f32x4*>(p + 4);
  bf16x8 r;
  r[0] = (short)f32_to_bf16_rne(lo[0]);
  r[1] = (short)f32_to_bf16_rne(lo[1]);
  r[2] = (short)f32_to_bf16_rne(lo[2]);
  r[3] = (short)f32_to_bf16_rne(lo[3]);
  r[4] = (short)f32_to_bf16_rne(hi[0]);
  r[5] = (short)f32_to_bf16_rne(hi[1]);
  r[6] = (short)f32_to_bf16_rne(hi[2]);
  r[7] = (short)f32_to_bf16_rne(hi[3]);
  return r;
}

// Grid: 1024 blocks = 128 row-groups x 8 j-chunks, 256 threads (4 waves).
// XCD-aware swizzle (T1). Swapped-Gram MFMA (R6 structure, proven).
// bf16 x-fragments converted INLINE from f32 x (x is 2MB -> L2-resident;
// same byte count per load as the old xb path, identical RNE rounding).
// No cvt kernel, no xb buffer. No device-scope fences (R7 lesson).
__global__ __launch_bounds__(256, 4) void main_kernel(
    const float* __restrict__ A,
    const float* __restrict__ x,
    float* __restrict__ spart) {
  int bid = blockIdx.x;
  int xcd = bid & 7;
  int slot = bid >> 3;               // 0..127 within XCD
  int rg = xcd * 16 + (slot & 15);   // contiguous 16 row-groups per XCD
  int js = slot >> 4;                // 0..7
  int tid = threadIdx.x;
  int w = tid >> 6;
  int lane = tid & 63;
  int i0 = rg * 64;
  int jbase = js * 1024 + w * 256;
  int c = lane & 15;   // operand row/col selector, D column (i)
  int q = lane >> 4;   // k-quad; D row group (j)

  // B-operand fragments (i-side), persistent: B[k][col=c] = X[i0+it*16+c][k]
  bf16x8 xi[4][2];
#pragma unroll
  for (int it = 0; it < 4; ++it)
#pragma unroll
    for (int kb = 0; kb < 2; ++kb)
      xi[it][kb] = cvt8(x + (size_t)(i0 + it * 16 + c) * DIM + kb * 32 + q * 8);

  // Per-it A row pointer: row i0+it*16+c, col jbase + q*4 (+ jt*16 folds to imm)
  const float* pA[4];
#pragma unroll
  for (int it = 0; it < 4; ++it)
    pA[it] = A + (size_t)(i0 + it * 16 + c) * N + jbase + q * 4;

  float sacc[4] = {0.f, 0.f, 0.f, 0.f};

  f32x4 a_buf[2][4];
  bf16x8 xj_buf[2][2];

  // prologue: jt=0 loads
#pragma unroll
  for (int it = 0; it < 4; ++it)
    a_buf[0][it] = *reinterpret_cast<const f32x4*>(pA[it]);
  {
    const float* pj = x + (size_t)(jbase + c) * DIM + q * 8;
    xj_buf[0][0] = cvt8(pj);
    xj_buf[0][1] = cvt8(pj + 32);
  }

#pragma unroll
  for (int jt = 0; jt < 16; ++jt) {
    const int cur = jt & 1, nxt = cur ^ 1;
    if (jt < 15) {
#pragma unroll
      for (int it = 0; it < 4; ++it)
        a_buf[nxt][it] =
            *reinterpret_cast<const f32x4*>(pA[it] + (jt + 1) * 16);
      const float* pj = x + (size_t)(jbase + (jt + 1) * 16 + c) * DIM + q * 8;
      xj_buf[nxt][0] = cvt8(pj);
      xj_buf[nxt][1] = cvt8(pj + 32);
    }
#pragma unroll
    for (int it = 0; it < 4; ++it) {
      f32x4 g = {0.f, 0.f, 0.f, 0.f};
      g = __builtin_amdgcn_mfma_f32_16x16x32_bf16(xj_buf[cur][0], xi[it][0], g, 0, 0, 0);
      g = __builtin_amdgcn_mfma_f32_16x16x32_bf16(xj_buf[cur][1], xi[it][1], g, 0, 0, 0);
      f32x4 a4 = a_buf[cur][it];
      sacc[it] = fmaf(a4[0], g[0], sacc[it]);
      sacc[it] = fmaf(a4[1], g[1], sacc[it]);
      sacc[it] = fmaf(a4[2], g[2], sacc[it]);
      sacc[it] = fmaf(a4[3], g[3], sacc[it]);
    }
  }

  // Sum over q (j sub-blocks within the wave): lanes c, c+16, c+32, c+48
#pragma unroll
  for (int it = 0; it < 4; ++it) {
    float s = sacc[it];
    s += __shfl_xor(s, 16);
    s += __shfl_xor(s, 32);
    sacc[it] = s;
  }

  __shared__ float red[4][64];
  if (q == 0) {
#pragma unroll
    for (int it = 0; it < 4; ++it)
      red[w][it * 16 + c] = sacc[it];
  }
  __syncthreads();
  if (tid < 64) {
    float s = red[0][tid] + red[1][tid] + red[2][tid] + red[3][tid];
    spart[(size_t)(i0 + tid) * 8 + js] = s;   // [i][js] layout: finish reads 32B runs
  }
}

// out[i][d] = 1 - 0.1*x[i][d] - 0.01*sum_js spart[i][js]; 131072 threads, 4 elems each
__global__ void finish_kernel(const float* __restrict__ x,
                              const float* __restrict__ spart,
                              float* __restrict__ out) {
  int gid = blockIdx.x * blockDim.x + threadIdx.x;
  float4 xv = reinterpret_cast<const float4*>(x)[gid];
  int i = gid >> 4;  // (gid*4)/64
  f32x4 p0 = *reinterpret_cast<const f32x4*>(spart + (size_t)i * 8);
  f32x4 p1 = *reinterpret_cast<const f32x4*>(spart + (size_t)i * 8 + 4);
  float s = ((p0[0] + p0[1]) + (p0[2] + p0[3])) + ((p1[0] + p1[1]) + (p1[2] + p1[3]));
  float4 o;
  o.x = 1.0f - 0.1f * xv.x - 0.01f * s;
  o.y = 1.0f - 0.1f * xv.y - 0.01f * s;
  o.z = 1.0f - 0.1f * xv.z - 0.01f * s;
  o.w = 1.0f - 0.1f * xv.w - 0.01f * s;
  reinterpret_cast<float4*>(out)[gid] = o;
}

extern "C" void kernel_launch(void* const* d_in, const int* in_sizes, int n_in,
                              void* d_out, int out_size, void* d_ws, size_t ws_size,
                              hipStream_t stream) {
  // d_in[0] = t (unused), d_in[1] = x f32 [8192][64], d_in[2] = A f32 [8192][8192]
  const float* x = (const float*)d_in[1];
  const float* A = (const float*)d_in[2];
  float* out = (float*)d_out;

  float* spart = (float*)d_ws;  // 256 KB partials, [8192][8] layout

  main_kernel<<<1024, 256, 0, stream>>>(A, x, spart);
  finish_kernel<<<512, 256, 0, stream>>>(x, spart, out);
}